// Round 5
// baseline (157.442 us; speedup 1.0000x reference)
//
#include <hip/hip_runtime.h>

// DiscriminatorIndependent: 1024 tiny MLPs (2->4->1, relu), B=16384.
//
// R1-R5: payload must use async global->LDS (gload_lds w=16); register-dest
//   loads get serialized by the compiler (R5: VGPR=48 chosen under a 128 cap).
// R6: occupancy 32->60% changed nothing. R7: atomics inside staging drains
//   poison the loop (WRITE 8.2MB). R8: halved DS work, regressed -> DS theory
//   dead. Surviving theory: __syncthreads() drains vmcnt(0) -> transfer and
//   compute never overlap inside a block; phases sum (delivered ~3.2 TB/s =
//   50% of the 6.3 TB/s streaming ceiling, VALUBusy 25%, nothing saturated).
//
// R9 = T3+T4 (counted vmcnt + raw s_barrier, never drain to 0 in the loop):
//   1024 blocks (4/CU), K=4 MLPs/thread -> full N per block -> block OWNS its
//   16 rows: direct out[] store, no atomics, no zero/combine kernels.
//   1 row/tile (4KB x + 4KB a), quad-buffered (32KB LDS), depth-3 prefetch:
//   stage(t+3) issued before compute(t); s_waitcnt vmcnt(6) keeps 3 tiles
//   (6 loads/wave) in flight across every barrier. Cross-wave combine is
//   deferred one tile (red[2][4]) -> ONE barrier per tile, lgkm drain is one
//   ds_write. Combining thread rotates across waves so its out-store never
//   over-constrains one wave's counted vmcnt.

constexpr int N_MLP = 1024;
constexpr int BATCH = 16384;
constexpr int NTHREADS = 256;   // 4 waves
constexpr int K = 4;            // MLPs per thread -> 256*4 = full N
constexpr int NBLK = 1024;      // 4 blocks/CU * 256 CU
constexpr int TILES = BATCH / NBLK;   // 16 rows per block, 1 row per tile
constexpr int PIPE = 4;         // quad buffer (depth-3 prefetch)

typedef __attribute__((address_space(3))) void lds_void;
typedef const __attribute__((address_space(1))) void gbl_void;

#define WAITVM(N)   asm volatile("s_waitcnt vmcnt(" #N ")" ::: "memory")
#define WAITLGKM0() asm volatile("s_waitcnt lgkmcnt(0)" ::: "memory")

__global__ __launch_bounds__(NTHREADS, 4)
void disc_mlp_kernel(const float* __restrict__ x,
                     const float* __restrict__ xa,
                     const float* __restrict__ W1,
                     const float* __restrict__ b1,
                     const float* __restrict__ W2,
                     const float* __restrict__ b2,
                     float* __restrict__ out)
{
    __shared__ float xbuf[PIPE][N_MLP];   // 16 KB
    __shared__ float abuf[PIPE][N_MLP];   // 16 KB
    __shared__ float red[2][NTHREADS / 64];

    const int t    = threadIdx.x;
    const int lane = t & 63;
    const int wave = t >> 6;
    const int r0   = blockIdx.x * TILES;  // this block's first row
    const int m0   = t * K;               // first of this thread's 4 MLPs

    // ---- params for 4 consecutive MLPs -> 65 regs, loaded once ----
    // W1[m] = 8 floats [h][e]: q0=(h0e0,h0e1,h1e0,h1e1), q1=(h2e0,...)
    float4 q0[4], q1[4], bv[4], wv[4];
#pragma unroll
    for (int m = 0; m < 4; ++m) {
        q0[m] = reinterpret_cast<const float4*>(W1)[(size_t)(m0 + m) * 2];
        q1[m] = reinterpret_cast<const float4*>(W1)[(size_t)(m0 + m) * 2 + 1];
        bv[m] = reinterpret_cast<const float4*>(b1)[m0 + m];
        wv[m] = reinterpret_cast<const float4*>(W2)[m0 + m];
    }
    const float4 b2v = reinterpret_cast<const float4*>(b2)[t];
    const float bsum = (b2v.x + b2v.y) + (b2v.z + b2v.w);

    // wave w stages quarter w of the row for both arrays: 2 gload_lds/wave/tile
    auto stage = [&](int tt) {
        const int buf = tt & (PIPE - 1);
        const size_t off = (size_t)(r0 + tt) * N_MLP + wave * 256 + lane * 4;
        __builtin_amdgcn_global_load_lds((gbl_void*)(x + off),
            (lds_void*)&xbuf[buf][wave * 256 + lane * 4], 16, 0, 0);
        __builtin_amdgcn_global_load_lds((gbl_void*)(xa + off),
            (lds_void*)&abuf[buf][wave * 256 + lane * 4], 16, 0, 0);
    };

    // one tile's work: combine tile tt-1 (deferred), compute tile tt
    auto body = [&](int tt) {
        __builtin_amdgcn_sched_barrier(0);
        if (tt > 0 && t == ((tt & 3) << 6)) {   // rotating combiner thread
            const int pb = (tt - 1) & 1;
            float v = (red[pb][0] + red[pb][1]) + (red[pb][2] + red[pb][3]);
            out[r0 + tt - 1] = v * (1.0f / (float)N_MLP);
        }
        const int buf = tt & (PIPE - 1);
        const float4 xv = reinterpret_cast<const float4*>(xbuf[buf])[t];
        const float4 av = reinterpret_cast<const float4*>(abuf[buf])[t];
        const float xe[4] = {xv.x, xv.y, xv.z, xv.w};
        const float ae[4] = {av.x, av.y, av.z, av.w};
        float s = bsum;
#pragma unroll
        for (int m = 0; m < 4; ++m) {
            float h0 = fmaf(q0[m].x, xe[m], fmaf(q0[m].y, ae[m], bv[m].x));
            float h1 = fmaf(q0[m].z, xe[m], fmaf(q0[m].w, ae[m], bv[m].y));
            float h2 = fmaf(q1[m].x, xe[m], fmaf(q1[m].y, ae[m], bv[m].z));
            float h3 = fmaf(q1[m].z, xe[m], fmaf(q1[m].w, ae[m], bv[m].w));
            s = fmaf(wv[m].x, fmaxf(h0, 0.0f), s);
            s = fmaf(wv[m].y, fmaxf(h1, 0.0f), s);
            s = fmaf(wv[m].z, fmaxf(h2, 0.0f), s);
            s = fmaf(wv[m].w, fmaxf(h3, 0.0f), s);
        }
        s += __shfl_down(s, 32);
        s += __shfl_down(s, 16);
        s += __shfl_down(s, 8);
        s += __shfl_down(s, 4);
        s += __shfl_down(s, 2);
        s += __shfl_down(s, 1);
        if (lane == 0) red[tt & 1][wave] = s;
    };

    // ---- prologue: 3 tiles in flight ----
    stage(0); stage(1); stage(2);

    // ---- main loop: counted vmcnt, loads always span the barrier ----
    for (int tt = 0; tt < TILES - 3; ++tt) {
        stage(tt + 3);              // 8 loads outstanding
        WAITVM(6);                  // tile tt resident; 3 tiles still in flight
        WAITLGKM0();                // red[tt-1] write (lane0) complete
        __builtin_amdgcn_s_barrier();
        body(tt);
    }
    // ---- epilogue: drain 4,2,0 ----
    WAITVM(4); WAITLGKM0(); __builtin_amdgcn_s_barrier(); body(TILES - 3);
    WAITVM(2); WAITLGKM0(); __builtin_amdgcn_s_barrier(); body(TILES - 2);
    WAITVM(0); WAITLGKM0(); __builtin_amdgcn_s_barrier(); body(TILES - 1);

    // final deferred combine
    WAITLGKM0();
    __builtin_amdgcn_s_barrier();
    if (t == ((TILES & 3) << 6)) {
        const int pb = (TILES - 1) & 1;
        float v = (red[pb][0] + red[pb][1]) + (red[pb][2] + red[pb][3]);
        out[r0 + TILES - 1] = v * (1.0f / (float)N_MLP);
    }
}

extern "C" void kernel_launch(void* const* d_in, const int* in_sizes, int n_in,
                              void* d_out, int out_size, void* d_ws, size_t ws_size,
                              hipStream_t stream) {
    const float* x  = (const float*)d_in[0];
    const float* xa = (const float*)d_in[1];
    const float* W1 = (const float*)d_in[2];
    const float* b1 = (const float*)d_in[3];
    const float* W2 = (const float*)d_in[4];
    const float* b2 = (const float*)d_in[5];
    float* out = (float*)d_out;

    disc_mlp_kernel<<<NBLK, NTHREADS, 0, stream>>>(x, xa, W1, b1, W2, b2, out);
}